// Round 15
// baseline (10321.746 us; speedup 1.0000x reference)
//
#include <hip/hip_runtime.h>

// Problem constants
#define TT   1024      // timesteps
#define BB   64        // batch
#define FF   256       // input features
#define HH   2048      // LSTM units
#define G4   8192      // 4*H
#define KTOT 2304      // F + H
#define KP   2312      // padded LDS K-stride for weight staging (elements)
#define NBLK 256
#define NTHR 512       // 8 waves -> 2 waves/SIMD
#define NWAVE 8
#define WL_BYTES (32 * KP * 2)            // 147,968 B weight staging (dead after init)
#define SMEM_BYTES WL_BYTES               // zl[8][32][68] f32 (69,632 B) overlays Wl
#define HSLOT16 (NBLK * 512)              // u16 elements per h slot (256 KB)
#define HBYTES ((size_t)HSLOT16 * 2)      // one h slot: 262,144 B
#define NREP 8                            // stamp replicas (one per XCD)
#define POLL_CAP (1 << 17)                // bounded spin: wrong-answer beats hang

typedef __attribute__((ext_vector_type(8))) short bf16x8;
typedef __attribute__((ext_vector_type(4))) float f32x4;

__device__ __forceinline__ unsigned short f2bf(float f) {
  unsigned u = __float_as_uint(f);
  u += 0x7FFFu + ((u >> 16) & 1u);        // RNE
  return (unsigned short)(u >> 16);
}
__device__ __forceinline__ float bf2f(unsigned short b) {
  return __uint_as_float((unsigned)b << 16);
}
__device__ __forceinline__ float sigm(float x) { return 1.0f / (1.0f + __expf(-x)); }
__device__ __forceinline__ float tanhfast(float x) {
  x = fminf(fmaxf(x, -15.0f), 15.0f);
  float e = __expf(2.0f * x);
  return (e - 1.0f) / (e + 1.0f);
}

// Persistent LSTM, barrier-free dataflow, 8-wave TLP, blocked h layout,
// XCD stamp replicas, R=8 rotation (r13 base) + FINE-GRAINED GATING:
// each wave's 256-wide k-slice = 8 groups of 32 k = 4 producer blocks each
// (one per lane-quarter). Per group: spin on its 4 stamps, compute its
// 4 loads + 8 MFMAs, with the NEXT group's stamp probe issued before the
// compute so the poll round-trip hides under it. Early producers' data is
// consumed immediately -> global-max skew becomes pipelined average.
__global__ void __launch_bounds__(NTHR, 2) lstm_persist(
    const float* __restrict__ x,          // [B][T][F] fp32
    const float* __restrict__ Wk,         // [F][4H]
    const float* __restrict__ Wr,         // [H][4H]
    const float* __restrict__ bias,       // [4H]
    unsigned short* __restrict__ hbufs,   // R x [jblk][b][8] u16 rotation
    unsigned* __restrict__ stamps,        // u32[NREP][256] replicated step stamps
    int rmask)                            // R-1 (R = pow2)
{
  extern __shared__ char smem[];
  unsigned short* Wl = (unsigned short*)smem;   // weight staging, dead after init
  float* zl = (float*)smem;                     // [8][32][68] partial-z overlay

  const int tid = threadIdx.x;
  const int j = blockIdx.x;
  const int lane = tid & 63;
  const int wid  = tid >> 6;               // 0..7  (K-slice owner)
  const int cl   = lane & 15;
  const int ko   = (lane >> 4) * 8;
  const int rg   = lane >> 4;

  // physical XCD of this CU (uniform within the block); replica selector only
  unsigned xcd;
  asm("s_getreg_b32 %0, hwreg(HW_REG_XCC_ID)" : "=s"(xcd));
  xcd &= (NREP - 1);

  // ---- stage weight slice into LDS (coalesced, one-time) ----
  for (int idx = tid; idx < 32 * KTOT; idx += NTHR) {
    int cc = idx & 31;
    int k  = idx >> 5;
    int zc = (cc >> 3) * HH + j * 8 + (cc & 7);
    float wv = (k < FF) ? Wk[(size_t)k * G4 + zc] : Wr[(size_t)(k - FF) * G4 + zc];
    Wl[cc * KP + k] = f2bf(wv);
  }
  __syncthreads();

  // ---- extract this wave's B fragments into registers (one-time) ----
  // wave wid: x k in [wid*32, +32) (s=0); h k in [wid*256, +256) (s=1..8)
  bf16x8 bfr[2][9];
  #pragma unroll
  for (int n = 0; n < 2; ++n) {
    #pragma unroll
    for (int s = 0; s < 9; ++s) {
      int kbase = (s == 0) ? (wid * 32)
                           : (FF + wid * 256 + (s - 1) * 32);
      bfr[n][s] = *(const bf16x8*)(Wl + (n * 16 + cl) * KP + kbase + ko);
    }
  }
  __syncthreads();   // Wl dead; zl overlay live from here

  // gate mapping (threads 0..255): thread -> (batch row bb, col pair col0..+1)
  const int hc2  = (tid & 3) * 2;
  const int bb   = tid >> 2;               // 0..63 for tid<256
  const int col0 = j * 8 + hc2;
  const float bi0 = bias[col0],          bi1 = bias[col0 + 1];
  const float bf0 = bias[HH + col0],     bf1 = bias[HH + col0 + 1];
  const float bg0 = bias[2*HH + col0],   bg1 = bias[2*HH + col0 + 1];
  const float bo0 = bias[3*HH + col0],   bo1 = bias[3*HH + col0 + 1];
  float cA = 0.0f, cB = 0.0f;

  // per-lane producer pointer: group s of wave wid -> block wid*32 + s*4 + (lane>>4)
  const unsigned* spb = stamps + (size_t)xcd * NBLK + wid * 32 + (lane >> 4);

  f32x4 acc[4][2];

#define XPART(TS) do {                                                        \
    _Pragma("unroll")                                                         \
    for (int m = 0; m < 4; ++m) {                                             \
      acc[m][0] = (f32x4){0.f,0.f,0.f,0.f};                                   \
      acc[m][1] = (f32x4){0.f,0.f,0.f,0.f};                                   \
    }                                                                         \
    {                                                                         \
      const int kx = wid * 32 + ko;                                           \
      _Pragma("unroll")                                                       \
      for (int m = 0; m < 4; ++m) {                                           \
        const float* xr = x + ((size_t)(m*16 + cl) * TT + (TS)) * FF + kx;    \
        const float4 v0 = *(const float4*)(xr);                               \
        const float4 v1 = *(const float4*)(xr + 4);                           \
        bf16x8 a;                                                             \
        a[0] = (short)f2bf(v0.x); a[1] = (short)f2bf(v0.y);                   \
        a[2] = (short)f2bf(v0.z); a[3] = (short)f2bf(v0.w);                   \
        a[4] = (short)f2bf(v1.x); a[5] = (short)f2bf(v1.y);                   \
        a[6] = (short)f2bf(v1.z); a[7] = (short)f2bf(v1.w);                   \
        acc[m][0] = __builtin_amdgcn_mfma_f32_16x16x32_bf16(a, bfr[0][0], acc[m][0], 0, 0, 0); \
        acc[m][1] = __builtin_amdgcn_mfma_f32_16x16x32_bf16(a, bfr[1][0], acc[m][1], 0, 0, 0); \
      }                                                                       \
    }                                                                         \
  } while (0)

  XPART(0);

  for (int t = 0; t < TT; ++t) {
    // ---- periodic acquire fence: covers rotation-slot reuse + replay ----
    if ((t & rmask) == 0) {
      if (tid < 64) __builtin_amdgcn_fence(__ATOMIC_ACQUIRE, "agent");
      __syncthreads();
    }

    // ---- h part: 8 producer-groups, per-group gating, pipelined polls ----
    const unsigned short* hb = hbufs + (size_t)(t & rmask) * HSLOT16;
    {
      unsigned v = (t > 0)
          ? __hip_atomic_load(spb, __ATOMIC_RELAXED, __HIP_MEMORY_SCOPE_AGENT)
          : 0u;
      #pragma unroll
      for (int s = 0; s < 8; ++s) {
        if (t > 0) {
          int it = 0;
          while (!__all((int)(v >= (unsigned)t))) {     // gate group s
            if (++it >= POLL_CAP) break;                // bounded: wrong > hang
            v = __hip_atomic_load(spb + s * 4, __ATOMIC_RELAXED,
                                  __HIP_MEMORY_SCOPE_AGENT);
          }
          asm volatile("" ::: "memory");                // loads stay below gate
          __builtin_amdgcn_sched_barrier(0);
        }
        // issue next group's probe BEFORE compute (RT hides under MFMAs)
        unsigned vnext = v;
        if (t > 0 && s < 7)
          vnext = __hip_atomic_load(spb + (s + 1) * 4, __ATOMIC_RELAXED,
                                    __HIP_MEMORY_SCOPE_AGENT);
        const int kh = wid * 256 + s * 32 + ko;
        const unsigned short* hkb = hb + ((size_t)(kh >> 3) << 9);
        #pragma unroll
        for (int m = 0; m < 4; ++m) {
          bf16x8 a = *(const bf16x8*)(hkb + (size_t)(m * 16 + cl) * 8);
          acc[m][0] = __builtin_amdgcn_mfma_f32_16x16x32_bf16(a, bfr[0][1 + s], acc[m][0], 0, 0, 0);
          acc[m][1] = __builtin_amdgcn_mfma_f32_16x16x32_bf16(a, bfr[1][1 + s], acc[m][1], 0, 0, 0);
        }
        v = vnext;
      }
    }

    // ---- write partial z to LDS: zl[wid][col][bb] ----
    #pragma unroll
    for (int m = 0; m < 4; ++m)
      #pragma unroll
      for (int n = 0; n < 2; ++n)
        *(f32x4*)(zl + (size_t)(wid * 32 + n * 16 + cl) * 68 + m * 16 + rg * 4) = acc[m][n];
    __syncthreads();

    // ---- gates (threads 0..255): sum 8 wave-partials, activate, update c ----
    if (tid < 256) {
      float zs[8];
      #pragma unroll
      for (int g = 0; g < 4; ++g) {
        float s0 = 0.f, s1 = 0.f;
        #pragma unroll
        for (int w = 0; w < NWAVE; ++w) {
          s0 += zl[(size_t)(w * 32 + g * 8 + hc2)     * 68 + bb];
          s1 += zl[(size_t)(w * 32 + g * 8 + hc2 + 1) * 68 + bb];
        }
        zs[2*g] = s0; zs[2*g+1] = s1;
      }
      float iA = sigm(zs[0] + bi0), iB = sigm(zs[1] + bi1);
      float fA = sigm(zs[2] + bf0), fB = sigm(zs[3] + bf1);
      float gA = tanhfast(zs[4] + bg0), gB = tanhfast(zs[5] + bg1);
      float oA = sigm(zs[6] + bo0), oB = sigm(zs[7] + bo1);
      cA = fA * cA + iA * gA;
      cB = fB * cB + iB * gB;
      float hA = oA * tanhfast(cA);
      float hB = oB * tanhfast(cB);
      // COALESCED publish: u32 store at slot + j*256 + tid (full lines)
      unsigned* hw = (unsigned*)(hbufs + (size_t)((t + 1) & rmask) * HSLOT16)
                     + j * 256 + tid;
      unsigned hp = (unsigned)f2bf(hA) | ((unsigned)f2bf(hB) << 16);
      __hip_atomic_store(hw, hp, __ATOMIC_RELAXED, __HIP_MEMORY_SCOPE_AGENT);
    }

    // ---- publish stamps (all replicas) + XPART overlap (no barrier) ----
    if (t + 1 < TT) {
      asm volatile("s_waitcnt vmcnt(0)" ::: "memory");   // h lines at LLC
      __syncthreads();                                   // block drained; zl free
      if (tid < NREP)                                    // one store per replica
        __hip_atomic_store(&stamps[(size_t)tid * NBLK + j], (unsigned)(t + 1),
                           __ATOMIC_RELAXED, __HIP_MEMORY_SCOPE_AGENT);
      asm volatile("" ::: "memory");                     // keep stamps before XPART
      XPART(t + 1);                                      // overlap consumers' polls
    }
  }
#undef XPART
}

// Fused epilogue: out = relu(relu(hT @ Wd + bd) @ Wo + bo).
// hT = rotation slot 0 (TT % R == 0), blocked: h[b][k] = s0[(k>>3)*512 + b*8 + (k&7)].
__global__ void dense_fused(const unsigned short* __restrict__ hT,
                            const float* __restrict__ Wd,
                            const float* __restrict__ bd,
                            const float* __restrict__ Wo,
                            const float* __restrict__ bo,
                            float* __restrict__ out) {
  __shared__ float hrow[HH];
  __shared__ float y1s[512];
  __shared__ float red[256];
  const int b = blockIdx.x, tid = threadIdx.x;
  for (int k = tid; k < HH; k += 256)
    hrow[k] = bf2f(hT[((size_t)(k >> 3) << 9) + b * 8 + (k & 7)]);
  __syncthreads();
  for (int c = tid; c < 512; c += 256) {
    float acc = bd[c];
    #pragma unroll 8
    for (int k = 0; k < HH; ++k) acc = fmaf(hrow[k], Wd[(size_t)k * 512 + c], acc);
    y1s[c] = fmaxf(acc, 0.0f);
  }
  __syncthreads();
  red[tid] = y1s[tid] * Wo[tid] + y1s[tid + 256] * Wo[tid + 256];
  __syncthreads();
  for (int st = 128; st > 0; st >>= 1) {
    if (tid < st) red[tid] += red[tid + st];
    __syncthreads();
  }
  if (tid == 0) out[b] = fmaxf(red[0] + bo[0], 0.0f);
}

extern "C" void kernel_launch(void* const* d_in, const int* in_sizes, int n_in,
                              void* d_out, int out_size, void* d_ws, size_t ws_size,
                              hipStream_t stream) {
  const float* x    = (const float*)d_in[0];
  const float* Wk   = (const float*)d_in[1];
  const float* Wr   = (const float*)d_in[2];
  const float* bias = (const float*)d_in[3];
  const float* Wd   = (const float*)d_in[4];
  const float* bd   = (const float*)d_in[5];
  const float* Wo   = (const float*)d_in[6];
  const float* bo   = (const float*)d_in[7];
  float* out = (float*)d_out;

  // Rotation depth: R=8 if workspace allows, else R=4.
  const size_t stamp_bytes = NREP * NBLK * sizeof(unsigned);   // 8 KB
  int R = 8;
  if ((size_t)R * HBYTES + stamp_bytes > ws_size) R = 4;
  const int rmask = R - 1;

  char* w = (char*)d_ws;
  unsigned short* hbufs = (unsigned short*)w;                   // R*256KB
  unsigned* stamps      = (unsigned*)(w + (size_t)R * HBYTES);  // 8 KB

  // deterministic per-call init (graph-replay safe)
  hipMemsetAsync(hbufs, 0, HBYTES, stream);       // h(0) = 0 in slot 0
  hipMemsetAsync(stamps, 0, stamp_bytes, stream);

  hipFuncSetAttribute((const void*)lstm_persist,
                      hipFuncAttributeMaxDynamicSharedMemorySize, SMEM_BYTES);

  void* args[] = { (void*)&x, (void*)&Wk, (void*)&Wr, (void*)&bias,
                   (void*)&hbufs, (void*)&stamps, (void*)&rmask };
  hipLaunchCooperativeKernel((const void*)lstm_persist, dim3(NBLK), dim3(NTHR),
                             args, SMEM_BYTES, stream);

  dense_fused<<<dim3(BB), dim3(256), 0, stream>>>(hbufs /*slot 0 = h_T*/,
                                                  Wd, bd, Wo, bo, out);
}

// Round 16
// 9340.870 us; speedup vs baseline: 1.1050x; 1.1050x over previous
//
#include <hip/hip_runtime.h>

// Problem constants
#define TT   1024      // timesteps
#define BB   64        // batch
#define FF   256       // input features
#define HH   2048      // LSTM units
#define G4   8192      // 4*H
#define KTOT 2304      // F + H
#define KP   2312      // padded LDS K-stride for weight staging (elements)
#define NBLK 256
#define NTHR 512       // 8 waves -> 2 waves/SIMD
#define NWAVE 8
#define WL_BYTES (32 * KP * 2)            // 147,968 B weight staging (dead after init)
#define SMEM_BYTES WL_BYTES               // zl[8][32][68] f32 (69,632 B) overlays Wl
#define HSLOT16 (NBLK * 512)              // u16 elements per h slot (256 KB)
#define HBYTES ((size_t)HSLOT16 * 2)      // one h slot: 262,144 B
#define NREP 8                            // stamp replicas (one per XCD)
#define POLL_CAP (1 << 17)                // bounded spin: wrong-answer beats hang

typedef __attribute__((ext_vector_type(8))) short bf16x8;
typedef __attribute__((ext_vector_type(4))) float f32x4;

__device__ __forceinline__ unsigned short f2bf(float f) {
  unsigned u = __float_as_uint(f);
  u += 0x7FFFu + ((u >> 16) & 1u);        // RNE
  return (unsigned short)(u >> 16);
}
__device__ __forceinline__ float bf2f(unsigned short b) {
  return __uint_as_float((unsigned)b << 16);
}
__device__ __forceinline__ float sigm(float x) { return 1.0f / (1.0f + __expf(-x)); }
__device__ __forceinline__ float tanhfast(float x) {
  x = fminf(fmaxf(x, -15.0f), 15.0f);
  float e = __expf(2.0f * x);
  return (e - 1.0f) / (e + 1.0f);
}

// Persistent LSTM, barrier-free dataflow, 8-wave TLP, blocked h layout (r11)
// + stamp REPLICAS (one per XCD) + R=8 rotation. Best verified config (r13).
__global__ void __launch_bounds__(NTHR, 2) lstm_persist(
    const float* __restrict__ x,          // [B][T][F] fp32
    const float* __restrict__ Wk,         // [F][4H]
    const float* __restrict__ Wr,         // [H][4H]
    const float* __restrict__ bias,       // [4H]
    unsigned short* __restrict__ hbufs,   // R x [jblk][b][8] u16 rotation
    unsigned* __restrict__ stamps,        // u32[NREP][256] replicated step stamps
    int rmask)                            // R-1 (R = pow2)
{
  extern __shared__ char smem[];
  unsigned short* Wl = (unsigned short*)smem;   // weight staging, dead after init
  float* zl = (float*)smem;                     // [8][32][68] partial-z overlay

  const int tid = threadIdx.x;
  const int j = blockIdx.x;
  const int lane = tid & 63;
  const int wid  = tid >> 6;               // 0..7  (K-slice owner)
  const int cl   = lane & 15;
  const int ko   = (lane >> 4) * 8;
  const int rg   = lane >> 4;

  // physical XCD of this CU (uniform within the block); replica selector only
  unsigned xcd;
  asm("s_getreg_b32 %0, hwreg(HW_REG_XCC_ID)" : "=s"(xcd));
  xcd &= (NREP - 1);

  // ---- stage weight slice into LDS (coalesced, one-time) ----
  for (int idx = tid; idx < 32 * KTOT; idx += NTHR) {
    int cc = idx & 31;
    int k  = idx >> 5;
    int zc = (cc >> 3) * HH + j * 8 + (cc & 7);
    float wv = (k < FF) ? Wk[(size_t)k * G4 + zc] : Wr[(size_t)(k - FF) * G4 + zc];
    Wl[cc * KP + k] = f2bf(wv);
  }
  __syncthreads();

  // ---- extract this wave's B fragments into registers (one-time) ----
  // wave wid: x k in [wid*32, +32) (s=0); h k in [wid*256, +256) (s=1..8)
  bf16x8 bfr[2][9];
  #pragma unroll
  for (int n = 0; n < 2; ++n) {
    #pragma unroll
    for (int s = 0; s < 9; ++s) {
      int kbase = (s == 0) ? (wid * 32)
                           : (FF + wid * 256 + (s - 1) * 32);
      bfr[n][s] = *(const bf16x8*)(Wl + (n * 16 + cl) * KP + kbase + ko);
    }
  }
  __syncthreads();   // Wl dead; zl overlay live from here

  // gate mapping (threads 0..255): thread -> (batch row bb, col pair col0..+1)
  const int hc2  = (tid & 3) * 2;
  const int bb   = tid >> 2;               // 0..63 for tid<256
  const int col0 = j * 8 + hc2;
  const float bi0 = bias[col0],          bi1 = bias[col0 + 1];
  const float bf0 = bias[HH + col0],     bf1 = bias[HH + col0 + 1];
  const float bg0 = bias[2*HH + col0],   bg1 = bias[2*HH + col0 + 1];
  const float bo0 = bias[3*HH + col0],   bo1 = bias[3*HH + col0 + 1];
  float cA = 0.0f, cB = 0.0f;

  f32x4 acc[4][2];

#define XPART(TS) do {                                                        \
    _Pragma("unroll")                                                         \
    for (int m = 0; m < 4; ++m) {                                             \
      acc[m][0] = (f32x4){0.f,0.f,0.f,0.f};                                   \
      acc[m][1] = (f32x4){0.f,0.f,0.f,0.f};                                   \
    }                                                                         \
    {                                                                         \
      const int kx = wid * 32 + ko;                                           \
      _Pragma("unroll")                                                       \
      for (int m = 0; m < 4; ++m) {                                           \
        const float* xr = x + ((size_t)(m*16 + cl) * TT + (TS)) * FF + kx;    \
        const float4 v0 = *(const float4*)(xr);                               \
        const float4 v1 = *(const float4*)(xr + 4);                           \
        bf16x8 a;                                                             \
        a[0] = (short)f2bf(v0.x); a[1] = (short)f2bf(v0.y);                   \
        a[2] = (short)f2bf(v0.z); a[3] = (short)f2bf(v0.w);                   \
        a[4] = (short)f2bf(v1.x); a[5] = (short)f2bf(v1.y);                   \
        a[6] = (short)f2bf(v1.z); a[7] = (short)f2bf(v1.w);                   \
        acc[m][0] = __builtin_amdgcn_mfma_f32_16x16x32_bf16(a, bfr[0][0], acc[m][0], 0, 0, 0); \
        acc[m][1] = __builtin_amdgcn_mfma_f32_16x16x32_bf16(a, bfr[1][0], acc[m][1], 0, 0, 0); \
      }                                                                       \
    }                                                                         \
  } while (0)

  XPART(0);

  for (int t = 0; t < TT; ++t) {
    // ---- periodic acquire fence: covers rotation-slot reuse + replay ----
    if ((t & rmask) == 0) {
      if (tid < 64) __builtin_amdgcn_fence(__ATOMIC_ACQUIRE, "agent");
      __syncthreads();
    }

    // ---- per-wave stamp wait on OWN-XCD replica: producers [32wid, +32) ----
    if (t > 0) {
      const unsigned* sp = stamps + (size_t)xcd * NBLK + wid * 32 + (lane & 31);
      for (int it = 0; it < POLL_CAP; ++it) {
        unsigned v = __hip_atomic_load(sp, __ATOMIC_RELAXED, __HIP_MEMORY_SCOPE_AGENT);
        if (__all((int)(v >= (unsigned)t))) break;
      }
      asm volatile("" ::: "memory");   // no h-load hoists above the poll
      __builtin_amdgcn_sched_barrier(0);
    }

    // ---- h part: wave's 256-wide K slice, blocked layout, cached loads ----
    // fragment (row, kh..kh+7) = hb + (kh>>3)*512 + row*8  (16B aligned)
    const unsigned short* hb = hbufs + (size_t)(t & rmask) * HSLOT16;
    #pragma unroll
    for (int s = 1; s < 9; ++s) {
      const int kh = wid * 256 + (s - 1) * 32 + ko;
      const unsigned short* hkb = hb + ((size_t)(kh >> 3) << 9);
      #pragma unroll
      for (int m = 0; m < 4; ++m) {
        bf16x8 a = *(const bf16x8*)(hkb + (size_t)(m * 16 + cl) * 8);
        acc[m][0] = __builtin_amdgcn_mfma_f32_16x16x32_bf16(a, bfr[0][s], acc[m][0], 0, 0, 0);
        acc[m][1] = __builtin_amdgcn_mfma_f32_16x16x32_bf16(a, bfr[1][s], acc[m][1], 0, 0, 0);
      }
    }

    // ---- write partial z to LDS: zl[wid][col][bb] ----
    #pragma unroll
    for (int m = 0; m < 4; ++m)
      #pragma unroll
      for (int n = 0; n < 2; ++n)
        *(f32x4*)(zl + (size_t)(wid * 32 + n * 16 + cl) * 68 + m * 16 + rg * 4) = acc[m][n];
    __syncthreads();

    // ---- gates (threads 0..255): sum 8 wave-partials, activate, update c ----
    if (tid < 256) {
      float zs[8];
      #pragma unroll
      for (int g = 0; g < 4; ++g) {
        float s0 = 0.f, s1 = 0.f;
        #pragma unroll
        for (int w = 0; w < NWAVE; ++w) {
          s0 += zl[(size_t)(w * 32 + g * 8 + hc2)     * 68 + bb];
          s1 += zl[(size_t)(w * 32 + g * 8 + hc2 + 1) * 68 + bb];
        }
        zs[2*g] = s0; zs[2*g+1] = s1;
      }
      float iA = sigm(zs[0] + bi0), iB = sigm(zs[1] + bi1);
      float fA = sigm(zs[2] + bf0), fB = sigm(zs[3] + bf1);
      float gA = tanhfast(zs[4] + bg0), gB = tanhfast(zs[5] + bg1);
      float oA = sigm(zs[6] + bo0), oB = sigm(zs[7] + bo1);
      cA = fA * cA + iA * gA;
      cB = fB * cB + iB * gB;
      float hA = oA * tanhfast(cA);
      float hB = oB * tanhfast(cB);
      // COALESCED publish: u32 store at slot + j*256 + tid (full lines)
      unsigned* hw = (unsigned*)(hbufs + (size_t)((t + 1) & rmask) * HSLOT16)
                     + j * 256 + tid;
      unsigned hp = (unsigned)f2bf(hA) | ((unsigned)f2bf(hB) << 16);
      __hip_atomic_store(hw, hp, __ATOMIC_RELAXED, __HIP_MEMORY_SCOPE_AGENT);
    }

    // ---- publish stamps (all replicas) + XPART overlap (no barrier) ----
    if (t + 1 < TT) {
      asm volatile("s_waitcnt vmcnt(0)" ::: "memory");   // h lines at LLC
      __syncthreads();                                   // block drained; zl free
      if (tid < NREP)                                    // one store per replica
        __hip_atomic_store(&stamps[(size_t)tid * NBLK + j], (unsigned)(t + 1),
                           __ATOMIC_RELAXED, __HIP_MEMORY_SCOPE_AGENT);
      asm volatile("" ::: "memory");                     // keep stamps before XPART
      XPART(t + 1);                                      // overlap consumers' polls
    }
  }
#undef XPART
}

// Fused epilogue: out = relu(relu(hT @ Wd + bd) @ Wo + bo).
// hT = rotation slot 0 (TT % R == 0), blocked: h[b][k] = s0[(k>>3)*512 + b*8 + (k&7)].
__global__ void dense_fused(const unsigned short* __restrict__ hT,
                            const float* __restrict__ Wd,
                            const float* __restrict__ bd,
                            const float* __restrict__ Wo,
                            const float* __restrict__ bo,
                            float* __restrict__ out) {
  __shared__ float hrow[HH];
  __shared__ float y1s[512];
  __shared__ float red[256];
  const int b = blockIdx.x, tid = threadIdx.x;
  for (int k = tid; k < HH; k += 256)
    hrow[k] = bf2f(hT[((size_t)(k >> 3) << 9) + b * 8 + (k & 7)]);
  __syncthreads();
  for (int c = tid; c < 512; c += 256) {
    float acc = bd[c];
    #pragma unroll 8
    for (int k = 0; k < HH; ++k) acc = fmaf(hrow[k], Wd[(size_t)k * 512 + c], acc);
    y1s[c] = fmaxf(acc, 0.0f);
  }
  __syncthreads();
  red[tid] = y1s[tid] * Wo[tid] + y1s[tid + 256] * Wo[tid + 256];
  __syncthreads();
  for (int st = 128; st > 0; st >>= 1) {
    if (tid < st) red[tid] += red[tid + st];
    __syncthreads();
  }
  if (tid == 0) out[b] = fmaxf(red[0] + bo[0], 0.0f);
}

extern "C" void kernel_launch(void* const* d_in, const int* in_sizes, int n_in,
                              void* d_out, int out_size, void* d_ws, size_t ws_size,
                              hipStream_t stream) {
  const float* x    = (const float*)d_in[0];
  const float* Wk   = (const float*)d_in[1];
  const float* Wr   = (const float*)d_in[2];
  const float* bias = (const float*)d_in[3];
  const float* Wd   = (const float*)d_in[4];
  const float* bd   = (const float*)d_in[5];
  const float* Wo   = (const float*)d_in[6];
  const float* bo   = (const float*)d_in[7];
  float* out = (float*)d_out;

  // Rotation depth: R=8 if workspace allows, else R=4.
  const size_t stamp_bytes = NREP * NBLK * sizeof(unsigned);   // 8 KB
  int R = 8;
  if ((size_t)R * HBYTES + stamp_bytes > ws_size) R = 4;
  const int rmask = R - 1;

  char* w = (char*)d_ws;
  unsigned short* hbufs = (unsigned short*)w;                   // R*256KB
  unsigned* stamps      = (unsigned*)(w + (size_t)R * HBYTES);  // 8 KB

  // deterministic per-call init (graph-replay safe)
  hipMemsetAsync(hbufs, 0, HBYTES, stream);       // h(0) = 0 in slot 0
  hipMemsetAsync(stamps, 0, stamp_bytes, stream);

  hipFuncSetAttribute((const void*)lstm_persist,
                      hipFuncAttributeMaxDynamicSharedMemorySize, SMEM_BYTES);

  void* args[] = { (void*)&x, (void*)&Wk, (void*)&Wr, (void*)&bias,
                   (void*)&hbufs, (void*)&stamps, (void*)&rmask };
  hipLaunchCooperativeKernel((const void*)lstm_persist, dim3(NBLK), dim3(NTHR),
                             args, SMEM_BYTES, stream);

  dense_fused<<<dim3(BB), dim3(256), 0, stream>>>(hbufs /*slot 0 = h_T*/,
                                                  Wd, bd, Wo, bo, out);
}